// Round 9
// baseline (400.557 us; speedup 1.0000x reference)
//
#include <hip/hip_runtime.h>
#include <hip/hip_bf16.h>
#include <math.h>

#define NNODES 20000
#define NEDGES 400000
#define NREL 8

typedef _Float16 h16_t;
typedef _Float16 h16x8 __attribute__((ext_vector_type(8)));
typedef _Float16 h16x4 __attribute__((ext_vector_type(4)));
typedef _Float16 h16x2 __attribute__((ext_vector_type(2)));
typedef float f32x4 __attribute__((ext_vector_type(4)));

struct W3 {
    const float* Wrel[3];
    const float* Wroot[3];
    const float* asrc[3];
    const float* adst[3];
    h16_t* B2[3];
};

// ---------------------------------------------------------------------------
// Merged: count_edges (blocks [0,1563)) + rel_proj (8) + watt (1728) +
// B2 transpose-pack (360 tile-blocks, coalesced reads + LDS transpose —
// replaces the 1KB-strided 4B column gather that over-fetched ~16x).
// ---------------------------------------------------------------------------
#define CEB 1563
__global__ __launch_bounds__(256) void pre_setup(
    W3 w, const int* __restrict__ ei, const int* __restrict__ et,
    int* __restrict__ relcnt, const float* __restrict__ rel_emb,
    const float* __restrict__ rpw, const float* __restrict__ rpb,
    float* __restrict__ rel_proj, float* __restrict__ watt, int E) {
    __shared__ float tile[64][65];
    const int bb = blockIdx.x;
    if (bb < CEB) {
        int e = bb * 256 + threadIdx.x;
        if (e < E) {
            int d = ei[E + e];
            atomicAdd(&relcnt[d * NREL + et[e]], 1);
        }
        return;
    }
    const int b = bb - CEB;
    if (b < 8) {
        int r = b, j = threadIdx.x;
        float acc = rpb[j];
        for (int i = 0; i < 256; ++i) acc += rel_emb[r * 256 + i] * rpw[i * 256 + j];
        rel_proj[r * 256 + j] = acc;
    } else if (b < 8 + 1728) {
        const int wg = (b - 8) * 4 + (threadIdx.x >> 6);
        const int lane = threadIdx.x & 63;
        const int layer = wg / (9 * 256);
        const int rem = wg % (9 * 256);
        const int idx = rem >> 8, k = rem & 255;
        const int dout = (layer == 2) ? 128 : 256;
        float a = 0.f;
        if (idx < NREL) {
            const float* wrow = w.Wrel[layer] + ((size_t)idx * 256 + k) * dout;
            const float* att = w.asrc[layer];
            for (int j = lane; j < dout; j += 64) a += wrow[j] * att[j];
        } else {
            const float* wrow = w.Wroot[layer] + (size_t)k * dout;
            const float* att = w.adst[layer];
            for (int j = lane; j < dout; j += 64) a += wrow[j] * att[j];
        }
        for (int o = 32; o > 0; o >>= 1) a += __shfl_xor(a, o);
        if (lane == 0) watt[(layer * 9 + idx) * 256 + k] = a;
    } else {
        // B2 pack via 64x64 LDS transpose. Matrices: per layer, 8x Wrel[r]
        // ([256 x dout]) + Wroot ([256 x dout]); dest B2[n][k] = src[k][j],
        // n = base + j. Layers 0/1: 9 mats x 16 tiles; layer 2: 9 x 8.
        int bp = b - 1736;
        int layer, m, tj, tk;
        if (bp < 288) {
            layer = bp / 144;
            int rem = bp % 144;
            m = rem >> 4;
            tj = rem & 3;
            tk = (rem >> 2) & 3;
        } else {
            layer = 2;
            int rem = bp - 288;
            m = rem >> 3;
            tj = rem & 1;
            tk = (rem >> 1) & 3;
        }
        const int dout = (layer == 2) ? 128 : 256;
        const int RD = NREL * dout;
        const float* src = (m < 8) ? (w.Wrel[layer] + (size_t)m * 256 * dout)
                                   : w.Wroot[layer];
        const int base = (m < 8) ? m * dout : RD;
        const int tx = threadIdx.x & 63, ty = threadIdx.x >> 6;
        const int k0 = tk * 64, j0 = tj * 64;
#pragma unroll
        for (int i = 0; i < 16; ++i) {
            int kk = i * 4 + ty;
            tile[kk][tx] = src[(size_t)(k0 + kk) * dout + j0 + tx];
        }
        __syncthreads();
        h16_t* Bd = w.B2[layer];
#pragma unroll
        for (int i = 0; i < 16; ++i) {
            int jj = i * 4 + ty;
            Bd[(size_t)(base + j0 + jj) * 256 + k0 + tx] = (h16_t)tile[tx][jj];
        }
    }
}

// ---------------------------------------------------------------------------
// Single-pass fused scan over deg := rowsum(relcnt)  (R8-verified).
// ---------------------------------------------------------------------------
__global__ __launch_bounds__(1024) void fused_scan(
    const int* __restrict__ relcnt, int* __restrict__ off,
    int* __restrict__ cursor, int* __restrict__ partials,
    int* __restrict__ ready, int n, int nb) {
    __shared__ int wsum[16];
    __shared__ int sbase;
    const int i = blockIdx.x * 1024 + threadIdx.x;
    const int lane = threadIdx.x & 63, wid = threadIdx.x >> 6;
    int d = 0;
    if (i < n) {
        const int4* p = (const int4*)(relcnt + (size_t)i * NREL);
        int4 a = p[0], b = p[1];
        d = a.x + a.y + a.z + a.w + b.x + b.y + b.z + b.w;
    }
    int s = d;
#pragma unroll
    for (int o = 1; o < 64; o <<= 1) {
        int t = __shfl_up(s, o);
        if (lane >= o) s += t;
    }
    if (lane == 63) wsum[wid] = s;
    __syncthreads();
    if (wid == 0 && lane < 16) {
        int ws = wsum[lane];
#pragma unroll
        for (int o = 1; o < 16; o <<= 1) {
            int t = __shfl_up(ws, o);
            if (lane >= o) ws += t;
        }
        wsum[lane] = ws;
    }
    __syncthreads();
    const int excl = ((wid == 0) ? 0 : wsum[wid - 1]) + s - d;
    const int btot = wsum[15];
    if (threadIdx.x == 0) {
        partials[blockIdx.x] = btot;
        __threadfence();                       // partials visible before count
        atomicAdd(ready, 1);
        while (atomicAdd(ready, 0) < nb) { }   // all blocks posted
        __threadfence();                       // acquire partials
    }
    __syncthreads();
    if (wid == 0) {
        int pv = (lane < nb) ? partials[lane] : 0;
        int ps = pv;
#pragma unroll
        for (int o = 1; o < 64; o <<= 1) {
            int t = __shfl_up(ps, o);
            if (lane >= o) ps += t;
        }
        if (lane == blockIdx.x) sbase = ps - pv;         // exclusive base
        if (blockIdx.x == 0 && lane == nb - 1) off[n] = ps;  // grand total
    }
    __syncthreads();
    if (i < n) {
        int v = sbase + excl;
        off[i] = v;
        cursor[i] = v;
    }
}

// ---------------------------------------------------------------------------
// Merged: scatter_edges (blocks [0,1563)) + cast_score (x -> A2 + 9 dots).
// ---------------------------------------------------------------------------
__global__ __launch_bounds__(256) void scat_cast(
    const int* __restrict__ ei, const int* __restrict__ et,
    int* __restrict__ cursor, int* __restrict__ sorted,
    const float* __restrict__ h, const float* __restrict__ watt,
    h16_t* __restrict__ A2, float* __restrict__ s_src,
    float* __restrict__ s_dst, int E, int n) {
    const int bb = blockIdx.x;
    if (bb < CEB) {
        int e = bb * 256 + threadIdx.x;
        if (e < E) {
            int d = ei[E + e];
            int pos = atomicAdd(&cursor[d], 1);
            sorted[pos] = (ei[e] << 3) | et[e];
        }
        return;
    }
    const int node = ((bb - CEB) * 256 + (int)threadIdx.x) >> 6;
    const int lane = threadIdx.x & 63;
    if (node >= n) return;
    float4 v = *(const float4*)(h + (size_t)node * 256 + lane * 4);
    h16x4 hi = {(h16_t)v.x, (h16_t)v.y, (h16_t)v.z, (h16_t)v.w};
    *(h16x4*)(A2 + (size_t)node * 256 + lane * 4) = hi;
#pragma unroll
    for (int idx = 0; idx < 9; ++idx) {
        const float* wv = watt + idx * 256 + lane * 4;
        float a = v.x * wv[0] + v.y * wv[1] + v.z * wv[2] + v.w * wv[3];
        for (int o = 32; o > 0; o >>= 1) a += __shfl_xor(a, o);
        if (lane == 0) {
            if (idx < NREL) s_src[node * NREL + idx] = a;
            else            s_dst[node] = a;
        }
    }
}

// ---------------------------------------------------------------------------
// fp16 GEMM, K=256 (R3/R6-verified) + coalesced LDS-staged epilogue.
// ---------------------------------------------------------------------------
#define GBM 128
#define GBN 128
#define GBK 64

__global__ __launch_bounds__(256) void gemm_mfma(
    const h16_t* __restrict__ A2, const h16_t* __restrict__ B2,
    h16_t* __restrict__ hrf, h16_t* __restrict__ rootf, int M, int dout) {
    constexpr int K = 256;
    const int RD = NREL * dout;
    __shared__ __align__(16) h16_t smem[GBM * GBK + GBN * GBK];  // 32 KB
    h16_t* As = smem;
    h16_t* Bs = smem + GBM * GBK;
    const int tid  = threadIdx.x;
    const int lane = tid & 63;
    const int w    = tid >> 6;
    const int row0 = blockIdx.y * GBM;
    const int col0 = blockIdx.x * GBN;
    const int wm   = (w >> 1) * 64;
    const int wn   = (w & 1) * 64;

    f32x4 acc[4][4] = {};

    for (int kb = 0; kb < K; kb += GBK) {
#pragma unroll
        for (int i = 0; i < 4; ++i) {
            int c  = i * 256 + tid;
            int r  = c >> 3;
            int cl = (c & 7) ^ (r & 7);
            int ra = row0 + r; if (ra >= M) ra = M - 1;
            const h16_t* ga = A2 + (size_t)ra * K + kb + cl * 8;
            __builtin_amdgcn_global_load_lds(
                (const __attribute__((address_space(1))) void*)ga,
                (__attribute__((address_space(3))) void*)(As + (size_t)c * 8), 16, 0, 0);
            const h16_t* gb = B2 + (size_t)(col0 + r) * K + kb + cl * 8;
            __builtin_amdgcn_global_load_lds(
                (const __attribute__((address_space(1))) void*)gb,
                (__attribute__((address_space(3))) void*)(Bs + (size_t)c * 8), 16, 0, 0);
        }
        __syncthreads();

        const int q = lane >> 4;
#pragma unroll
        for (int kk = 0; kk < 2; ++kk) {
            const int cf = kk * 4 + q;
            h16x8 af[4], bfr[4];
#pragma unroll
            for (int t = 0; t < 4; ++t) {
                int rr = wm + t * 16 + (lane & 15);
                af[t] = *(const h16x8*)(As + rr * GBK + (cf ^ (rr & 7)) * 8);
                int rc = wn + t * 16 + (lane & 15);
                bfr[t] = *(const h16x8*)(Bs + rc * GBK + (cf ^ (rc & 7)) * 8);
            }
#pragma unroll
            for (int mt = 0; mt < 4; ++mt)
#pragma unroll
                for (int nt = 0; nt < 4; ++nt)
                    acc[mt][nt] = __builtin_amdgcn_mfma_f32_16x16x32_f16(
                        af[mt], bfr[nt], acc[mt][nt], 0, 0, 0);
        }
        __syncthreads();   // also guarantees As/Bs free for C-tile staging
    }

    // ---- coalesced epilogue: acc -> LDS (128x128 h16) -> h16x8 stores ----
    h16_t* Ct = smem;
#pragma unroll
    for (int mt = 0; mt < 4; ++mt)
#pragma unroll
        for (int reg = 0; reg < 4; ++reg) {
            int rl = wm + mt * 16 + (lane >> 4) * 4 + reg;
#pragma unroll
            for (int nt = 0; nt < 4; ++nt) {
                int cl2 = wn + nt * 16 + (lane & 15);
                Ct[rl * 128 + cl2] = (h16_t)acc[mt][nt][reg];
            }
        }
    __syncthreads();

    const bool is_rel = (col0 < RD);
    h16_t* dstb = is_rel ? hrf : rootf;
    const int dstride = is_rel ? RD : dout;
    const int cbase = is_rel ? col0 : col0 - RD;
#pragma unroll
    for (int it = 0; it < 8; ++it) {
        int u  = it * 256 + tid;     // 0..2047 units of 8 h16
        int rl = u >> 4;
        int cu = (u & 15) * 8;
        int row = row0 + rl;
        if (row < M)
            *(h16x8*)(dstb + (size_t)row * dstride + cbase + cu) =
                *(const h16x8*)(Ct + rl * 128 + cu);
    }
}

// ---------------------------------------------------------------------------
// Segment softmax + aggregation + epilogue — one wave per node (R2/R6-verified
// shfl form; residual read from A2out fp16 before overwrite).
// ---------------------------------------------------------------------------
template <int DO, int MODE>
__global__ __launch_bounds__(256) void attn_agg(
    const int* __restrict__ off, const int* __restrict__ sorted,
    const float* __restrict__ s_src, const float* __restrict__ s_dst,
    const h16_t* __restrict__ hrf, const h16_t* __restrict__ rootf,
    const int* __restrict__ relcnt, const float* __restrict__ relproj,
    float* __restrict__ out,
    const float* __restrict__ watt_next, h16_t* __restrict__ A2out,
    float* __restrict__ ssrc_out, float* __restrict__ sdst_out, int n) {
    const int node = (blockIdx.x * blockDim.x + threadIdx.x) >> 6;
    const int lane = threadIdx.x & 63;
    if (node >= n) return;
    const int beg = off[node];
    const int deg = off[node + 1] - beg;
    const float sdn = s_dst[node];
    constexpr int PER = DO / 64;
    float acc[PER];
#pragma unroll
    for (int j = 0; j < PER; ++j) acc[j] = 0.f;

    auto rowload = [&](int pj, float exj) {
        const h16_t* row = hrf + (size_t)(pj >> 3) * (NREL * DO) + (pj & 7) * DO;
        if constexpr (PER == 4) {
            h16x4 v = *(const h16x4*)(row + lane * 4);
            acc[0] += exj * (float)v[0]; acc[1] += exj * (float)v[1];
            acc[2] += exj * (float)v[2]; acc[3] += exj * (float)v[3];
        } else {
            h16x2 v = *(const h16x2*)(row + lane * 2);
            acc[0] += exj * (float)v[0]; acc[1] += exj * (float)v[1];
        }
    };

    if (deg > 0) {
        float inv;
        if (deg <= 64) {
            int p = 0; float sc = -1e30f;
            if (lane < deg) {
                p = sorted[beg + lane];
                sc = s_src[(p >> 3) * NREL + (p & 7)] + sdn;
                sc = sc > 0.f ? sc : 0.2f * sc;
            }
            float m = sc;
            for (int o = 32; o > 0; o >>= 1) m = fmaxf(m, __shfl_xor(m, o));
            float ex = (lane < deg) ? __expf(sc - m) : 0.f;
            float dsum = ex;
            for (int o = 32; o > 0; o >>= 1) dsum += __shfl_xor(dsum, o);
            int j = 0;
            for (; j + 8 <= deg; j += 8) {
#pragma unroll
                for (int u = 0; u < 8; ++u)
                    rowload(__shfl(p, j + u), __shfl(ex, j + u));
            }
            for (; j < deg; ++j) rowload(__shfl(p, j), __shfl(ex, j));
            inv = 1.f / dsum;
        } else {
            float m = -1e30f;
            for (int e = lane; e < deg; e += 64) {
                int p = sorted[beg + e];
                float sc = s_src[(p >> 3) * NREL + (p & 7)] + sdn;
                sc = sc > 0.f ? sc : 0.2f * sc;
                m = fmaxf(m, sc);
            }
            for (int o = 32; o > 0; o >>= 1) m = fmaxf(m, __shfl_xor(m, o));
            float dsum = 0.f;
            for (int e0 = 0; e0 < deg; e0 += 64) {
                int e = e0 + lane;
                int p = 0; float ex = 0.f;
                if (e < deg) {
                    p = sorted[beg + e];
                    float sc = s_src[(p >> 3) * NREL + (p & 7)] + sdn;
                    sc = sc > 0.f ? sc : 0.2f * sc;
                    ex = __expf(sc - m);
                    dsum += ex;
                }
                int cnt = deg - e0; if (cnt > 64) cnt = 64;
                int j = 0;
                for (; j + 8 <= cnt; j += 8) {
#pragma unroll
                    for (int u = 0; u < 8; ++u)
                        rowload(__shfl(p, j + u), __shfl(ex, j + u));
                }
                for (; j < cnt; ++j) rowload(__shfl(p, j), __shfl(ex, j));
            }
            for (int o = 32; o > 0; o >>= 1) dsum += __shfl_xor(dsum, o);
            inv = 1.f / dsum;
        }
#pragma unroll
        for (int j = 0; j < PER; ++j) acc[j] *= inv;
    }

    const int cbase = lane * PER;
    if constexpr (MODE == 0) {
        float rsum[PER];
#pragma unroll
        for (int j = 0; j < PER; ++j) rsum[j] = 0.f;
#pragma unroll
        for (int r = 0; r < NREL; ++r) {
            float cr = (float)relcnt[node * NREL + r];
            const float* rp = relproj + r * 256 + cbase;
#pragma unroll
            for (int j = 0; j < PER; ++j) rsum[j] += cr * rp[j];
        }
        h16x4 hp = *(const h16x4*)(A2out + (size_t)node * 256 + cbase);
        float t[PER];
#pragma unroll
        for (int j = 0; j < PER; ++j) {
            int c = cbase + j;
            float r_ = (float)rootf[(size_t)node * DO + c] + acc[j];
            float u = r_ + rsum[j];
            u = u > 0.f ? u : 0.f;
            t[j] = (float)hp[j] + u;
        }
        h16x4 hi;
#pragma unroll
        for (int j = 0; j < PER; ++j) hi[j] = (h16_t)t[j];
        *(h16x4*)(A2out + (size_t)node * 256 + cbase) = hi;
#pragma unroll
        for (int idx = 0; idx < 9; ++idx) {
            const float* wv = watt_next + idx * 256 + cbase;
            float a = 0.f;
#pragma unroll
            for (int j = 0; j < PER; ++j) a += t[j] * wv[j];
            for (int o = 32; o > 0; o >>= 1) a += __shfl_xor(a, o);
            if (lane == 0) {
                if (idx < NREL) ssrc_out[node * NREL + idx] = a;
                else            sdst_out[node] = a;
            }
        }
    } else {
#pragma unroll
        for (int j = 0; j < PER; ++j) {
            int c = cbase + j;
            out[(size_t)node * DO + c] = (float)rootf[(size_t)node * DO + c] + acc[j];
        }
    }
}

// ---------------------------------------------------------------------------
extern "C" void kernel_launch(void* const* d_in, const int* in_sizes, int n_in,
                              void* d_out, int out_size, void* d_ws, size_t ws_size,
                              hipStream_t stream) {
    const int N = NNODES, E = NEDGES;
    const float* x        = (const float*)d_in[0];
    const int*   ei       = (const int*)d_in[1];
    const int*   et       = (const int*)d_in[2];
    const float* rel_emb  = (const float*)d_in[3];
    const float* rpw      = (const float*)d_in[4];
    const float* rpb      = (const float*)d_in[5];
    float* outp = (float*)d_out;

    W3 w3;
    for (int l = 0; l < 3; ++l) {
        w3.Wrel[l]  = (const float*)d_in[6 + 4 * l];
        w3.Wroot[l] = (const float*)d_in[7 + 4 * l];
        w3.asrc[l]  = (const float*)d_in[8 + 4 * l];
        w3.adst[l]  = (const float*)d_in[9 + 4 * l];
    }

    // Workspace (~110 MB of 256 MiB budget).
    char* w = (char*)d_ws;
    auto alloc = [&](size_t bytes) { char* p = w; w += (bytes + 255) & ~(size_t)255; return p; };
    h16_t* hrf     = (h16_t*)alloc((size_t)N * 2048 * 2);   // 81.9 MB
    h16_t* rootf   = (h16_t*)alloc((size_t)N * 256 * 2);    // 10.2 MB
    float* relproj = (float*)alloc(NREL * 256 * 4);
    float* watt    = (float*)alloc(3 * 9 * 256 * 4);
    float* ssrcA   = (float*)alloc((size_t)N * NREL * 4);
    float* sdstA   = (float*)alloc((size_t)N * 4);
    float* ssrcB   = (float*)alloc((size_t)N * NREL * 4);
    float* sdstB   = (float*)alloc((size_t)N * 4);
    h16_t* A2      = (h16_t*)alloc((size_t)N * 256 * 2);    // 10.2 MB
    w3.B2[0]       = (h16_t*)alloc((size_t)2304 * 256 * 2); // 1.18 MB (L2-hot)
    w3.B2[1]       = (h16_t*)alloc((size_t)2304 * 256 * 2);
    w3.B2[2]       = (h16_t*)alloc((size_t)1152 * 256 * 2);
    int* relcnt    = (int*)alloc((size_t)N * NREL * 4);     // 640000 B (256-mult)
    int* ready     = (int*)alloc(256);                       // memset with relcnt
    int* off       = (int*)alloc((size_t)(N + 1) * 4);
    int* cursor    = (int*)alloc((size_t)N * 4);
    int* sorted    = (int*)alloc((size_t)E * 4);
    int* partials  = (int*)alloc(64 * 4);
    (void)ws_size; (void)in_sizes; (void)n_in; (void)out_size;

    // zero relcnt AND ready (contiguous) in one memset — re-poisons each replay
    hipMemsetAsync(relcnt, 0, (size_t)N * NREL * 4 + 256, stream);

    const int NB = (N + 1023) / 1024;   // 20 blocks
    // pre_setup: 1563 count + 8 relproj + 1728 watt + 360 B2-transpose
    pre_setup<<<CEB + 2096, 256, 0, stream>>>(w3, ei, et, relcnt, rel_emb,
                                              rpw, rpb, relproj, watt, E);
    fused_scan<<<NB, 1024, 0, stream>>>(relcnt, off, cursor, partials, ready, N, NB);

    const int ATB  = (N + 3) / 4;           // 5000
    const int MBLK = (N + GBM - 1) / GBM;   // 157
    scat_cast<<<CEB + ATB, 256, 0, stream>>>(ei, et, cursor, sorted,
                                             x, watt, A2, ssrcA, sdstA, E, N);

    // layer 0: x -> (A2 := h1 fp16)
    gemm_mfma<<<dim3(18, MBLK), 256, 0, stream>>>(A2, w3.B2[0], hrf, rootf, N, 256);
    attn_agg<256, 0><<<ATB, 256, 0, stream>>>(off, sorted, ssrcA, sdstA, hrf, rootf,
                                              relcnt, relproj, nullptr,
                                              watt + 9 * 256, A2, ssrcB, sdstB, N);
    // layer 1: (A2 := h2 fp16)
    gemm_mfma<<<dim3(18, MBLK), 256, 0, stream>>>(A2, w3.B2[1], hrf, rootf, N, 256);
    attn_agg<256, 0><<<ATB, 256, 0, stream>>>(off, sorted, ssrcB, sdstB, hrf, rootf,
                                              relcnt, relproj, nullptr,
                                              watt + 2 * 9 * 256, A2, ssrcA, sdstA, N);
    // layer 2: h2 -> out
    gemm_mfma<<<dim3(9, MBLK), 256, 0, stream>>>(A2, w3.B2[2], hrf, rootf, N, 128);
    attn_agg<128, 1><<<ATB, 256, 0, stream>>>(off, sorted, ssrcA, sdstA, hrf, rootf,
                                              nullptr, nullptr, outp,
                                              nullptr, nullptr, nullptr, nullptr, N);
}

// Round 10
// 382.226 us; speedup vs baseline: 1.0480x; 1.0480x over previous
//
#include <hip/hip_runtime.h>
#include <hip/hip_bf16.h>
#include <math.h>

#define NNODES 20000
#define NEDGES 400000
#define NREL 8

typedef _Float16 h16_t;
typedef _Float16 h16x8 __attribute__((ext_vector_type(8)));
typedef _Float16 h16x4 __attribute__((ext_vector_type(4)));
typedef _Float16 h16x2 __attribute__((ext_vector_type(2)));
typedef float f32x4 __attribute__((ext_vector_type(4)));

struct W3 {
    const float* Wrel[3];
    const float* Wroot[3];
    const float* asrc[3];
    const float* adst[3];
    h16_t* B2[3];
};

// ---------------------------------------------------------------------------
// Merged: count_edges (blocks [0,1563)) + rel_proj (8) + watt (1728) +
// B2 transpose-pack (360 tile-blocks, coalesced reads + LDS transpose).
// ---------------------------------------------------------------------------
#define CEB 1563
__global__ __launch_bounds__(256) void pre_setup(
    W3 w, const int* __restrict__ ei, const int* __restrict__ et,
    int* __restrict__ relcnt, const float* __restrict__ rel_emb,
    const float* __restrict__ rpw, const float* __restrict__ rpb,
    float* __restrict__ rel_proj, float* __restrict__ watt, int E) {
    __shared__ float tile[64][65];
    const int bb = blockIdx.x;
    if (bb < CEB) {
        int e = bb * 256 + threadIdx.x;
        if (e < E) {
            int d = ei[E + e];
            atomicAdd(&relcnt[d * NREL + et[e]], 1);
        }
        return;
    }
    const int b = bb - CEB;
    if (b < 8) {
        int r = b, j = threadIdx.x;
        float acc = rpb[j];
        for (int i = 0; i < 256; ++i) acc += rel_emb[r * 256 + i] * rpw[i * 256 + j];
        rel_proj[r * 256 + j] = acc;
    } else if (b < 8 + 1728) {
        const int wg = (b - 8) * 4 + (threadIdx.x >> 6);
        const int lane = threadIdx.x & 63;
        const int layer = wg / (9 * 256);
        const int rem = wg % (9 * 256);
        const int idx = rem >> 8, k = rem & 255;
        const int dout = (layer == 2) ? 128 : 256;
        float a = 0.f;
        if (idx < NREL) {
            const float* wrow = w.Wrel[layer] + ((size_t)idx * 256 + k) * dout;
            const float* att = w.asrc[layer];
            for (int j = lane; j < dout; j += 64) a += wrow[j] * att[j];
        } else {
            const float* wrow = w.Wroot[layer] + (size_t)k * dout;
            const float* att = w.adst[layer];
            for (int j = lane; j < dout; j += 64) a += wrow[j] * att[j];
        }
        for (int o = 32; o > 0; o >>= 1) a += __shfl_xor(a, o);
        if (lane == 0) watt[(layer * 9 + idx) * 256 + k] = a;
    } else {
        // B2 pack via 64x64 LDS transpose. dest B2[n][k] = src[k][j], n=base+j.
        int bp = b - 1736;
        int layer, m, tj, tk;
        if (bp < 288) {
            layer = bp / 144;
            int rem = bp % 144;
            m = rem >> 4;
            tj = rem & 3;
            tk = (rem >> 2) & 3;
        } else {
            layer = 2;
            int rem = bp - 288;
            m = rem >> 3;
            tj = rem & 1;
            tk = (rem >> 1) & 3;
        }
        const int dout = (layer == 2) ? 128 : 256;
        const int RD = NREL * dout;
        const float* src = (m < 8) ? (w.Wrel[layer] + (size_t)m * 256 * dout)
                                   : w.Wroot[layer];
        const int base = (m < 8) ? m * dout : RD;
        const int tx = threadIdx.x & 63, ty = threadIdx.x >> 6;
        const int k0 = tk * 64, j0 = tj * 64;
#pragma unroll
        for (int i = 0; i < 16; ++i) {
            int kk = i * 4 + ty;
            tile[kk][tx] = src[(size_t)(k0 + kk) * dout + j0 + tx];
        }
        __syncthreads();
        h16_t* Bd = w.B2[layer];
#pragma unroll
        for (int i = 0; i < 16; ++i) {
            int jj = i * 4 + ty;
            Bd[(size_t)(base + j0 + jj) * 256 + k0 + tx] = (h16_t)tile[tx][jj];
        }
    }
}

// ---------------------------------------------------------------------------
// Multi-block exclusive scan over deg := rowsum(relcnt)  (R1/R6-verified).
// ---------------------------------------------------------------------------
__global__ __launch_bounds__(1024) void scan_blocks(
    const int* __restrict__ relcnt, int* __restrict__ loc,
    int* __restrict__ partials, int n) {
    __shared__ int wsum[16];
    const int i = blockIdx.x * 1024 + threadIdx.x;
    const int lane = threadIdx.x & 63, wid = threadIdx.x >> 6;
    int d = 0;
    if (i < n) {
        const int4* p = (const int4*)(relcnt + (size_t)i * NREL);
        int4 a = p[0], b = p[1];
        d = a.x + a.y + a.z + a.w + b.x + b.y + b.z + b.w;
    }
    int s = d;
#pragma unroll
    for (int o = 1; o < 64; o <<= 1) {
        int t = __shfl_up(s, o);
        if (lane >= o) s += t;
    }
    if (lane == 63) wsum[wid] = s;
    __syncthreads();
    if (wid == 0 && lane < 16) {
        int ws = wsum[lane];
#pragma unroll
        for (int o = 1; o < 16; o <<= 1) {
            int t = __shfl_up(ws, o);
            if (lane >= o) ws += t;
        }
        wsum[lane] = ws;
    }
    __syncthreads();
    int excl = ((wid == 0) ? 0 : wsum[wid - 1]) + s - d;
    if (i < n) loc[i] = excl;
    if (threadIdx.x == 1023) partials[blockIdx.x] = wsum[15];
}

__global__ void scan_partials_k(int* __restrict__ partials, int* __restrict__ off,
                                int nb, int n) {
    const int lane = threadIdx.x;
    int v = (lane < nb) ? partials[lane] : 0;
    int s = v;
#pragma unroll
    for (int o = 1; o < 64; o <<= 1) {
        int t = __shfl_up(s, o);
        if (lane >= o) s += t;
    }
    if (lane < nb) partials[lane] = s - v;
    if (lane == 63) off[n] = s;
}

__global__ __launch_bounds__(1024) void add_offsets(
    const int* __restrict__ loc, const int* __restrict__ partials,
    int* __restrict__ off, int* __restrict__ cursor, int n) {
    const int i = blockIdx.x * 1024 + threadIdx.x;
    if (i >= n) return;
    int v = loc[i] + partials[blockIdx.x];
    off[i] = v;
    cursor[i] = v;
}

// ---------------------------------------------------------------------------
// Merged: scatter_edges (blocks [0,1563)) + cast_score (x -> A2 + 9 dots).
// ---------------------------------------------------------------------------
__global__ __launch_bounds__(256) void scat_cast(
    const int* __restrict__ ei, const int* __restrict__ et,
    int* __restrict__ cursor, int* __restrict__ sorted,
    const float* __restrict__ h, const float* __restrict__ watt,
    h16_t* __restrict__ A2, float* __restrict__ s_src,
    float* __restrict__ s_dst, int E, int n) {
    const int bb = blockIdx.x;
    if (bb < CEB) {
        int e = bb * 256 + threadIdx.x;
        if (e < E) {
            int d = ei[E + e];
            int pos = atomicAdd(&cursor[d], 1);
            sorted[pos] = (ei[e] << 3) | et[e];
        }
        return;
    }
    const int node = ((bb - CEB) * 256 + (int)threadIdx.x) >> 6;
    const int lane = threadIdx.x & 63;
    if (node >= n) return;
    float4 v = *(const float4*)(h + (size_t)node * 256 + lane * 4);
    h16x4 hi = {(h16_t)v.x, (h16_t)v.y, (h16_t)v.z, (h16_t)v.w};
    *(h16x4*)(A2 + (size_t)node * 256 + lane * 4) = hi;
#pragma unroll
    for (int idx = 0; idx < 9; ++idx) {
        const float* wv = watt + idx * 256 + lane * 4;
        float a = v.x * wv[0] + v.y * wv[1] + v.z * wv[2] + v.w * wv[3];
        for (int o = 32; o > 0; o >>= 1) a += __shfl_xor(a, o);
        if (lane == 0) {
            if (idx < NREL) s_src[node * NREL + idx] = a;
            else            s_dst[node] = a;
        }
    }
}

// ---------------------------------------------------------------------------
// fp16 GEMM, K=256 (R3/R6-verified) + coalesced LDS-staged epilogue.
// ---------------------------------------------------------------------------
#define GBM 128
#define GBN 128
#define GBK 64

__global__ __launch_bounds__(256) void gemm_mfma(
    const h16_t* __restrict__ A2, const h16_t* __restrict__ B2,
    h16_t* __restrict__ hrf, h16_t* __restrict__ rootf, int M, int dout) {
    constexpr int K = 256;
    const int RD = NREL * dout;
    __shared__ __align__(16) h16_t smem[GBM * GBK + GBN * GBK];  // 32 KB
    h16_t* As = smem;
    h16_t* Bs = smem + GBM * GBK;
    const int tid  = threadIdx.x;
    const int lane = tid & 63;
    const int w    = tid >> 6;
    const int row0 = blockIdx.y * GBM;
    const int col0 = blockIdx.x * GBN;
    const int wm   = (w >> 1) * 64;
    const int wn   = (w & 1) * 64;

    f32x4 acc[4][4] = {};

    for (int kb = 0; kb < K; kb += GBK) {
#pragma unroll
        for (int i = 0; i < 4; ++i) {
            int c  = i * 256 + tid;
            int r  = c >> 3;
            int cl = (c & 7) ^ (r & 7);
            int ra = row0 + r; if (ra >= M) ra = M - 1;
            const h16_t* ga = A2 + (size_t)ra * K + kb + cl * 8;
            __builtin_amdgcn_global_load_lds(
                (const __attribute__((address_space(1))) void*)ga,
                (__attribute__((address_space(3))) void*)(As + (size_t)c * 8), 16, 0, 0);
            const h16_t* gb = B2 + (size_t)(col0 + r) * K + kb + cl * 8;
            __builtin_amdgcn_global_load_lds(
                (const __attribute__((address_space(1))) void*)gb,
                (__attribute__((address_space(3))) void*)(Bs + (size_t)c * 8), 16, 0, 0);
        }
        __syncthreads();

        const int q = lane >> 4;
#pragma unroll
        for (int kk = 0; kk < 2; ++kk) {
            const int cf = kk * 4 + q;
            h16x8 af[4], bfr[4];
#pragma unroll
            for (int t = 0; t < 4; ++t) {
                int rr = wm + t * 16 + (lane & 15);
                af[t] = *(const h16x8*)(As + rr * GBK + (cf ^ (rr & 7)) * 8);
                int rc = wn + t * 16 + (lane & 15);
                bfr[t] = *(const h16x8*)(Bs + rc * GBK + (cf ^ (rc & 7)) * 8);
            }
#pragma unroll
            for (int mt = 0; mt < 4; ++mt)
#pragma unroll
                for (int nt = 0; nt < 4; ++nt)
                    acc[mt][nt] = __builtin_amdgcn_mfma_f32_16x16x32_f16(
                        af[mt], bfr[nt], acc[mt][nt], 0, 0, 0);
        }
        __syncthreads();   // also guarantees As/Bs free for C-tile staging
    }

    // ---- coalesced epilogue: acc -> LDS (128x128 h16) -> h16x8 stores ----
    h16_t* Ct = smem;
#pragma unroll
    for (int mt = 0; mt < 4; ++mt)
#pragma unroll
        for (int reg = 0; reg < 4; ++reg) {
            int rl = wm + mt * 16 + (lane >> 4) * 4 + reg;
#pragma unroll
            for (int nt = 0; nt < 4; ++nt) {
                int cl2 = wn + nt * 16 + (lane & 15);
                Ct[rl * 128 + cl2] = (h16_t)acc[mt][nt][reg];
            }
        }
    __syncthreads();

    const bool is_rel = (col0 < RD);
    h16_t* dstb = is_rel ? hrf : rootf;
    const int dstride = is_rel ? RD : dout;
    const int cbase = is_rel ? col0 : col0 - RD;
#pragma unroll
    for (int it = 0; it < 8; ++it) {
        int u  = it * 256 + tid;     // 0..2047 units of 8 h16
        int rl = u >> 4;
        int cu = (u & 15) * 8;
        int row = row0 + rl;
        if (row < M)
            *(h16x8*)(dstb + (size_t)row * dstride + cbase + cu) =
                *(const h16x8*)(Ct + rl * 128 + cu);
    }
}

// ---------------------------------------------------------------------------
// Segment softmax + aggregation + epilogue — one wave per node (R2/R6-verified
// shfl form). NEW: 128-thread (2-wave) blocks — block retirement is coupled
// to max of 2 node degrees instead of 4, raising achieved occupancy.
// ---------------------------------------------------------------------------
template <int DO, int MODE>
__global__ __launch_bounds__(128) void attn_agg(
    const int* __restrict__ off, const int* __restrict__ sorted,
    const float* __restrict__ s_src, const float* __restrict__ s_dst,
    const h16_t* __restrict__ hrf, const h16_t* __restrict__ rootf,
    const int* __restrict__ relcnt, const float* __restrict__ relproj,
    float* __restrict__ out,
    const float* __restrict__ watt_next, h16_t* __restrict__ A2out,
    float* __restrict__ ssrc_out, float* __restrict__ sdst_out, int n) {
    const int node = (blockIdx.x * blockDim.x + threadIdx.x) >> 6;
    const int lane = threadIdx.x & 63;
    if (node >= n) return;
    const int beg = off[node];
    const int deg = off[node + 1] - beg;
    const float sdn = s_dst[node];
    constexpr int PER = DO / 64;
    float acc[PER];
#pragma unroll
    for (int j = 0; j < PER; ++j) acc[j] = 0.f;

    auto rowload = [&](int pj, float exj) {
        const h16_t* row = hrf + (size_t)(pj >> 3) * (NREL * DO) + (pj & 7) * DO;
        if constexpr (PER == 4) {
            h16x4 v = *(const h16x4*)(row + lane * 4);
            acc[0] += exj * (float)v[0]; acc[1] += exj * (float)v[1];
            acc[2] += exj * (float)v[2]; acc[3] += exj * (float)v[3];
        } else {
            h16x2 v = *(const h16x2*)(row + lane * 2);
            acc[0] += exj * (float)v[0]; acc[1] += exj * (float)v[1];
        }
    };

    if (deg > 0) {
        float inv;
        if (deg <= 64) {
            int p = 0; float sc = -1e30f;
            if (lane < deg) {
                p = sorted[beg + lane];
                sc = s_src[(p >> 3) * NREL + (p & 7)] + sdn;
                sc = sc > 0.f ? sc : 0.2f * sc;
            }
            float m = sc;
            for (int o = 32; o > 0; o >>= 1) m = fmaxf(m, __shfl_xor(m, o));
            float ex = (lane < deg) ? __expf(sc - m) : 0.f;
            float dsum = ex;
            for (int o = 32; o > 0; o >>= 1) dsum += __shfl_xor(dsum, o);
            int j = 0;
            for (; j + 8 <= deg; j += 8) {
#pragma unroll
                for (int u = 0; u < 8; ++u)
                    rowload(__shfl(p, j + u), __shfl(ex, j + u));
            }
            for (; j < deg; ++j) rowload(__shfl(p, j), __shfl(ex, j));
            inv = 1.f / dsum;
        } else {
            float m = -1e30f;
            for (int e = lane; e < deg; e += 64) {
                int p = sorted[beg + e];
                float sc = s_src[(p >> 3) * NREL + (p & 7)] + sdn;
                sc = sc > 0.f ? sc : 0.2f * sc;
                m = fmaxf(m, sc);
            }
            for (int o = 32; o > 0; o >>= 1) m = fmaxf(m, __shfl_xor(m, o));
            float dsum = 0.f;
            for (int e0 = 0; e0 < deg; e0 += 64) {
                int e = e0 + lane;
                int p = 0; float ex = 0.f;
                if (e < deg) {
                    p = sorted[beg + e];
                    float sc = s_src[(p >> 3) * NREL + (p & 7)] + sdn;
                    sc = sc > 0.f ? sc : 0.2f * sc;
                    ex = __expf(sc - m);
                    dsum += ex;
                }
                int cnt = deg - e0; if (cnt > 64) cnt = 64;
                int j = 0;
                for (; j + 8 <= cnt; j += 8) {
#pragma unroll
                    for (int u = 0; u < 8; ++u)
                        rowload(__shfl(p, j + u), __shfl(ex, j + u));
                }
                for (; j < cnt; ++j) rowload(__shfl(p, j), __shfl(ex, j));
            }
            for (int o = 32; o > 0; o >>= 1) dsum += __shfl_xor(dsum, o);
            inv = 1.f / dsum;
        }
#pragma unroll
        for (int j = 0; j < PER; ++j) acc[j] *= inv;
    }

    const int cbase = lane * PER;
    if constexpr (MODE == 0) {
        float rsum[PER];
#pragma unroll
        for (int j = 0; j < PER; ++j) rsum[j] = 0.f;
#pragma unroll
        for (int r = 0; r < NREL; ++r) {
            float cr = (float)relcnt[node * NREL + r];
            const float* rp = relproj + r * 256 + cbase;
#pragma unroll
            for (int j = 0; j < PER; ++j) rsum[j] += cr * rp[j];
        }
        h16x4 hp = *(const h16x4*)(A2out + (size_t)node * 256 + cbase);
        float t[PER];
#pragma unroll
        for (int j = 0; j < PER; ++j) {
            int c = cbase + j;
            float r_ = (float)rootf[(size_t)node * DO + c] + acc[j];
            float u = r_ + rsum[j];
            u = u > 0.f ? u : 0.f;
            t[j] = (float)hp[j] + u;
        }
        h16x4 hi;
#pragma unroll
        for (int j = 0; j < PER; ++j) hi[j] = (h16_t)t[j];
        *(h16x4*)(A2out + (size_t)node * 256 + cbase) = hi;
#pragma unroll
        for (int idx = 0; idx < 9; ++idx) {
            const float* wv = watt_next + idx * 256 + cbase;
            float a = 0.f;
#pragma unroll
            for (int j = 0; j < PER; ++j) a += t[j] * wv[j];
            for (int o = 32; o > 0; o >>= 1) a += __shfl_xor(a, o);
            if (lane == 0) {
                if (idx < NREL) ssrc_out[node * NREL + idx] = a;
                else            sdst_out[node] = a;
            }
        }
    } else {
#pragma unroll
        for (int j = 0; j < PER; ++j) {
            int c = cbase + j;
            out[(size_t)node * DO + c] = (float)rootf[(size_t)node * DO + c] + acc[j];
        }
    }
}

// ---------------------------------------------------------------------------
extern "C" void kernel_launch(void* const* d_in, const int* in_sizes, int n_in,
                              void* d_out, int out_size, void* d_ws, size_t ws_size,
                              hipStream_t stream) {
    const int N = NNODES, E = NEDGES;
    const float* x        = (const float*)d_in[0];
    const int*   ei       = (const int*)d_in[1];
    const int*   et       = (const int*)d_in[2];
    const float* rel_emb  = (const float*)d_in[3];
    const float* rpw      = (const float*)d_in[4];
    const float* rpb      = (const float*)d_in[5];
    float* outp = (float*)d_out;

    W3 w3;
    for (int l = 0; l < 3; ++l) {
        w3.Wrel[l]  = (const float*)d_in[6 + 4 * l];
        w3.Wroot[l] = (const float*)d_in[7 + 4 * l];
        w3.asrc[l]  = (const float*)d_in[8 + 4 * l];
        w3.adst[l]  = (const float*)d_in[9 + 4 * l];
    }

    // Workspace (~110 MB of 256 MiB budget).
    char* w = (char*)d_ws;
    auto alloc = [&](size_t bytes) { char* p = w; w += (bytes + 255) & ~(size_t)255; return p; };
    h16_t* hrf     = (h16_t*)alloc((size_t)N * 2048 * 2);   // 81.9 MB
    h16_t* rootf   = (h16_t*)alloc((size_t)N * 256 * 2);    // 10.2 MB
    float* relproj = (float*)alloc(NREL * 256 * 4);
    float* watt    = (float*)alloc(3 * 9 * 256 * 4);
    float* ssrcA   = (float*)alloc((size_t)N * NREL * 4);
    float* sdstA   = (float*)alloc((size_t)N * 4);
    float* ssrcB   = (float*)alloc((size_t)N * NREL * 4);
    float* sdstB   = (float*)alloc((size_t)N * 4);
    h16_t* A2      = (h16_t*)alloc((size_t)N * 256 * 2);    // 10.2 MB
    w3.B2[0]       = (h16_t*)alloc((size_t)2304 * 256 * 2); // 1.18 MB (L2-hot)
    w3.B2[1]       = (h16_t*)alloc((size_t)2304 * 256 * 2);
    w3.B2[2]       = (h16_t*)alloc((size_t)1152 * 256 * 2);
    int* off       = (int*)alloc((size_t)(N + 1) * 4);
    int* cursor    = (int*)alloc((size_t)N * 4);
    int* relcnt    = (int*)alloc((size_t)N * NREL * 4);
    int* sorted    = (int*)alloc((size_t)E * 4);
    int* loc       = (int*)alloc((size_t)N * 4);
    int* partials  = (int*)alloc(64 * 4);
    (void)ws_size; (void)in_sizes; (void)n_in; (void)out_size;

    hipMemsetAsync(relcnt, 0, (size_t)N * NREL * 4, stream);

    const int NB = (N + 1023) / 1024;   // 20 blocks
    // pre_setup: 1563 count + 8 relproj + 1728 watt + 360 B2-transpose
    pre_setup<<<CEB + 2096, 256, 0, stream>>>(w3, ei, et, relcnt, rel_emb,
                                              rpw, rpb, relproj, watt, E);
    scan_blocks<<<NB, 1024, 0, stream>>>(relcnt, loc, partials, N);
    scan_partials_k<<<1, 64, 0, stream>>>(partials, off, NB, N);
    add_offsets<<<NB, 1024, 0, stream>>>(loc, partials, off, cursor, N);

    const int ATB  = (N + 3) / 4;           // 5000 (256-thread kernels)
    const int ATB2 = (N + 1) / 2;           // 10000 (128-thread attn blocks)
    const int MBLK = (N + GBM - 1) / GBM;   // 157
    scat_cast<<<CEB + ATB, 256, 0, stream>>>(ei, et, cursor, sorted,
                                             x, watt, A2, ssrcA, sdstA, E, N);

    // layer 0: x -> (A2 := h1 fp16)
    gemm_mfma<<<dim3(18, MBLK), 256, 0, stream>>>(A2, w3.B2[0], hrf, rootf, N, 256);
    attn_agg<256, 0><<<ATB2, 128, 0, stream>>>(off, sorted, ssrcA, sdstA, hrf, rootf,
                                               relcnt, relproj, nullptr,
                                               watt + 9 * 256, A2, ssrcB, sdstB, N);
    // layer 1: (A2 := h2 fp16)
    gemm_mfma<<<dim3(18, MBLK), 256, 0, stream>>>(A2, w3.B2[1], hrf, rootf, N, 256);
    attn_agg<256, 0><<<ATB2, 128, 0, stream>>>(off, sorted, ssrcB, sdstB, hrf, rootf,
                                               relcnt, relproj, nullptr,
                                               watt + 2 * 9 * 256, A2, ssrcA, sdstA, N);
    // layer 2: h2 -> out
    gemm_mfma<<<dim3(9, MBLK), 256, 0, stream>>>(A2, w3.B2[2], hrf, rootf, N, 128);
    attn_agg<128, 1><<<ATB2, 128, 0, stream>>>(off, sorted, ssrcA, sdstA, hrf, rootf,
                                               nullptr, nullptr, outp,
                                               nullptr, nullptr, nullptr, nullptr, N);
}